// Round 14
// baseline (68.372 us; speedup 1.0000x reference)
//
#include <hip/hip_runtime.h>
#include <math.h>

#define H 64
#define VOCAB 64
#define LSEQ 4096
#define NSLOTS 4
#define NP 3
#define EPS 1e-5f

typedef unsigned long long ull;

__device__ __forceinline__ float wsum(float x) {
    #pragma unroll
    for (int m = 1; m < 64; m <<= 1) x += __shfl_xor(x, m);
    return x;
}
__device__ __forceinline__ float wmax(float x) {
    #pragma unroll
    for (int m = 1; m < 64; m <<= 1) x = fmaxf(x, __shfl_xor(x, m));
    return x;
}
__device__ __forceinline__ void wb() { __builtin_amdgcn_wave_barrier(); }

// Single fused kernel: one block per batch, ZERO workspace, ZERO cross-block
// communication. Each block redundantly rebuilds the 64-row encoder table
// (hidden[v][:]) and scores in LDS, then runs selection + the 3-pass pipeline
// using FACTORED matvecs that never materialize Sk/Sv/MT:
//   logits[v] = (hidden[v].u + rk_b.sq) * scale,   u  = rk_w @ sq
//   attn@Sv   = rv_w^T @ g + denom * rv_b,         g[d] = sum_v w[v] hidden[v][d]
// Deterministic by construction -> replay-tripwire-safe (R10-R13 lesson).
__global__ __launch_bounds__(256) void fused_all(
    const int*   __restrict__ seq,
    const float* __restrict__ embed,
    const float* __restrict__ ff1_w, const float* __restrict__ ff1_b,
    const float* __restrict__ ff2_w, const float* __restrict__ ff2_b,
    const float* __restrict__ enc_g, const float* __restrict__ enc_b,
    const float* __restrict__ g1_w,  const float* __restrict__ g1_b,
    const float* __restrict__ g2_w,  const float* __restrict__ g2_b,
    const float* __restrict__ rq_w,  const float* __restrict__ rq_b,
    const float* __restrict__ rk_w,  const float* __restrict__ rk_b,
    const float* __restrict__ rv_w,  const float* __restrict__ rv_b,
    const float* __restrict__ rn_g,  const float* __restrict__ rn_b,
    const float* __restrict__ rd_q_w, const float* __restrict__ rd_q_b,
    const float* __restrict__ out_w, const float* __restrict__ out_b,
    float* __restrict__ out)
{
    __shared__ float hidT[64 * 65];     // hidT[d*65+v] = hidden[v][d]; stride 65 -> conflict-free both ways
    __shared__ float score_s[64];
    __shared__ int   whist[4][64];
    __shared__ float wslab[4][192];     // per-wave staging: [0..63] vec, [64..191] a1
    __shared__ float slN[4][64];
    __shared__ float l4[4];
    __shared__ float rbuf[64];

    const int bid = blockIdx.x, tid = threadIdx.x;
    const int wid = tid >> 6, lane = tid & 63;
    float* buf = wslab[wid];

    // ---- issue seq loads first (HBM latency hides under the encoder) ----
    const int4* s4 = (const int4*)(seq + (size_t)bid * LSEQ);
    int4 t0 = s4[tid];
    int4 t1 = s4[tid + 256];
    int4 t2 = s4[tid + 512];
    int4 t3 = s4[tid + 768];
    const int last = seq[(size_t)bid * LSEQ + LSEQ - 1];   // uniform
    whist[wid][lane] = 0;
    const float g2b0 = g2_b[0];

    // ---- encoder: wave wid computes tokens v = wid*16 + j ----
    for (int j = 0; j < 16; j++) {
        const int v = wid * 16 + j;
        float h = embed[v * 64 + lane];
        wb(); buf[lane] = h; wb();

        float a0 = ff1_b[lane], a1v = ff1_b[64 + lane], a0b = 0.f, a1b = 0.f;
        const float4* h4 = (const float4*)buf;
        #pragma unroll
        for (int d4 = 0; d4 < 16; d4++) {
            float4 hv = h4[d4]; const int d = d4 * 4;
            a0  += hv.x * ff1_w[(d + 0) * 128 + lane];
            a1v += hv.x * ff1_w[(d + 0) * 128 + 64 + lane];
            a0b += hv.y * ff1_w[(d + 1) * 128 + lane];
            a1b += hv.y * ff1_w[(d + 1) * 128 + 64 + lane];
            a0  += hv.z * ff1_w[(d + 2) * 128 + lane];
            a1v += hv.z * ff1_w[(d + 2) * 128 + 64 + lane];
            a0b += hv.w * ff1_w[(d + 3) * 128 + lane];
            a1b += hv.w * ff1_w[(d + 3) * 128 + 64 + lane];
        }
        wb();
        buf[64 + lane]  = fmaxf(a0 + a0b, 0.f);
        buf[128 + lane] = fmaxf(a1v + a1b, 0.f);
        wb();

        float o0 = ff2_b[lane], o1 = 0.f, o2 = 0.f, o3 = 0.f;
        const float4* A4 = (const float4*)(buf + 64);
        #pragma unroll
        for (int j4 = 0; j4 < 32; j4++) {
            float4 av = A4[j4]; const int jj = j4 * 4;
            o0 += av.x * ff2_w[(jj + 0) * 64 + lane];
            o1 += av.y * ff2_w[(jj + 1) * 64 + lane];
            o2 += av.z * ff2_w[(jj + 2) * 64 + lane];
            o3 += av.w * ff2_w[(jj + 3) * 64 + lane];
        }
        float x = h + ((o0 + o1) + (o2 + o3));
        float s1 = x, s2 = x * x;
        #pragma unroll
        for (int m = 1; m < 64; m <<= 1) { s1 += __shfl_xor(s1, m); s2 += __shfl_xor(s2, m); }
        float mu  = s1 * (1.f / 64.f);
        float var = s2 * (1.f / 64.f) - mu * mu;
        float hid = (x - mu) * rsqrtf(var + EPS) * enc_g[lane] + enc_b[lane];
        hidT[lane * 65 + v] = hid;                     // bank (lane+v)%32: free
        wb(); buf[lane] = hid; wb();

        // gate score
        float pa = 0.f;
        if (lane < 32) {
            float aa = g1_b[lane], ab = 0.f;
            const float4* d4p = (const float4*)buf;
            #pragma unroll
            for (int d4 = 0; d4 < 16; d4++) {
                float4 hv = d4p[d4]; const int d = d4 * 4;
                aa += hv.x * g1_w[(d + 0) * 32 + lane];
                ab += hv.y * g1_w[(d + 1) * 32 + lane];
                aa += hv.z * g1_w[(d + 2) * 32 + lane];
                ab += hv.w * g1_w[(d + 3) * 32 + lane];
            }
            pa = fmaxf(aa + ab, 0.f) * g2_w[lane];
        }
        float pt = wsum(pa);
        if (lane == 0) score_s[v] = 1.f / (1.f + expf(-(pt + g2b0)));
    }

    // ---- histogram (wave-private banks; seq has landed long ago) ----
    {
        int* hw = whist[wid];
        atomicAdd(&hw[t0.x], 1); atomicAdd(&hw[t0.y], 1);
        atomicAdd(&hw[t0.z], 1); atomicAdd(&hw[t0.w], 1);
        atomicAdd(&hw[t1.x], 1); atomicAdd(&hw[t1.y], 1);
        atomicAdd(&hw[t1.z], 1); atomicAdd(&hw[t1.w], 1);
        atomicAdd(&hw[t2.x], 1); atomicAdd(&hw[t2.y], 1);
        atomicAdd(&hw[t2.z], 1); atomicAdd(&hw[t2.w], 1);
        atomicAdd(&hw[t3.x], 1); atomicAdd(&hw[t3.y], 1);
        atomicAdd(&hw[t3.z], 1); atomicAdd(&hw[t3.w], 1);
    }
    __syncthreads();

    const int cnt = whist[0][lane] + whist[1][lane] + whist[2][lane] + whist[3][lane];
    const float cntf = (float)cnt;

    // ---- selection (greedy multiset by score desc, token asc; proven) ----
    int my_tok = 0;
    {
        float key = cnt > 0 ? score_s[lane] : -1.f;
        int filled = 0;
        bool have = false;
        #pragma unroll 1
        for (int r = 0; r < NSLOTS && filled < NSLOTS; r++) {
            float m2 = wmax(key);
            ull win = __ballot(key == m2);
            int tk = __ffsll(win) - 1;
            int c  = __shfl(cnt, tk);
            if (!have && (unsigned)(wid - filled) < (unsigned)c) { my_tok = tk; have = true; }
            filled += c;
            if (lane == tk) key = -1.f;
        }
    }

    // ---- 3-pass pipeline, factored matvecs (wave wid owns slot wid) ----
    float s = hidT[lane * 65 + my_tok];    // hidden[my_tok][lane]

    #pragma unroll
    for (int p = 0; p < NP; p++) {
        wb(); buf[lane] = s; wb();
        // sq = rq_w^T s + rq_b
        float q0 = rq_b[p * 64 + lane], q1 = 0.f, q2 = 0.f, q3 = 0.f;
        const float4* s4p = (const float4*)buf;
        #pragma unroll
        for (int d4 = 0; d4 < 16; d4++) {
            float4 sv = s4p[d4]; const int d = d4 * 4;
            q0 += sv.x * rq_w[(p * 64 + d + 0) * 64 + lane];
            q1 += sv.y * rq_w[(p * 64 + d + 1) * 64 + lane];
            q2 += sv.z * rq_w[(p * 64 + d + 2) * 64 + lane];
            q3 += sv.w * rq_w[(p * 64 + d + 3) * 64 + lane];
        }
        float sq = (q0 + q1) + (q2 + q3);
        float cterm = wsum(rk_b[p * 64 + lane] * sq);     // rk_b . sq
        wb(); buf[lane] = sq; wb();
        // u = rk_w @ sq (row per lane, float4)
        const float4* rk4 = (const float4*)(rk_w + (size_t)(p * 64 + lane) * 64);
        const float4* sq4 = (const float4*)buf;
        float u0 = 0.f, u1 = 0.f, u2 = 0.f, u3 = 0.f;
        #pragma unroll
        for (int k4 = 0; k4 < 16; k4++) {
            float4 wv = rk4[k4]; float4 qv = sq4[k4];
            u0 += wv.x * qv.x; u1 += wv.y * qv.y;
            u2 += wv.z * qv.z; u3 += wv.w * qv.w;
        }
        float u = (u0 + u1) + (u2 + u3);
        wb(); buf[lane] = u; wb();
        // logits over v = lane: hidden[v].u + cterm
        float l0 = 0.f, l1 = 0.f, l2 = 0.f, l3 = 0.f;
        #pragma unroll
        for (int d = 0; d < 64; d += 4) {
            l0 += hidT[(d + 0) * 65 + lane] * buf[d + 0];
            l1 += hidT[(d + 1) * 65 + lane] * buf[d + 1];
            l2 += hidT[(d + 2) * 65 + lane] * buf[d + 2];
            l3 += hidT[(d + 3) * 65 + lane] * buf[d + 3];
        }
        float lg = (cterm + ((l0 + l1) + (l2 + l3))) * 0.125f;
        float w = cntf * __expf(lg);                      // cnt==0 -> exactly 0
        float denom = wsum(w);
        wb(); buf[lane] = w; wb();
        // g[d=lane] = sum_v w[v] * hidden[v][d]
        const float* hrow = hidT + lane * 65;
        float g0 = 0.f, g1v = 0.f, g2v = 0.f, g3 = 0.f;
        #pragma unroll
        for (int v = 0; v < 64; v += 4) {
            g0  += buf[v + 0] * hrow[v + 0];
            g1v += buf[v + 1] * hrow[v + 1];
            g2v += buf[v + 2] * hrow[v + 2];
            g3  += buf[v + 3] * hrow[v + 3];
        }
        float g = (g0 + g1v) + (g2v + g3);
        wb(); buf[lane] = g; wb();
        // ao = rv_w^T g + denom*rv_b
        float b0 = denom * rv_b[p * 64 + lane], b1 = 0.f, b2 = 0.f, b3 = 0.f;
        const float4* g4 = (const float4*)buf;
        #pragma unroll
        for (int d4 = 0; d4 < 16; d4++) {
            float4 gv = g4[d4]; const int d = d4 * 4;
            b0 += gv.x * rv_w[(p * 64 + d + 0) * 64 + lane];
            b1 += gv.y * rv_w[(p * 64 + d + 1) * 64 + lane];
            b2 += gv.z * rv_w[(p * 64 + d + 2) * 64 + lane];
            b3 += gv.w * rv_w[(p * 64 + d + 3) * 64 + lane];
        }
        float ao = (b0 + b1) + (b2 + b3);
        // denom-folded LN (proven)
        float y = s * denom + ao;
        float s1 = y, s2v = y * y;
        #pragma unroll
        for (int m = 1; m < 64; m <<= 1) { s1 += __shfl_xor(s1, m); s2v += __shfl_xor(s2v, m); }
        float muy  = s1 * (1.f / 64.f);
        float vary = s2v * (1.f / 64.f) - muy * muy;
        s = (y - muy) * rsqrtf(vary + EPS * denom * denom) * rn_g[p * 64 + lane] + rn_b[p * 64 + lane];
    }

    // ---- read head ----
    float qa = rd_q_b[lane], qb = 0.f, qc = 0.f, qd = 0.f;
    #pragma unroll
    for (int d = 0; d < 64; d += 4) {
        qa += hidT[(d + 0) * 65 + last] * rd_q_w[(d + 0) * 64 + lane];
        qb += hidT[(d + 1) * 65 + last] * rd_q_w[(d + 1) * 64 + lane];
        qc += hidT[(d + 2) * 65 + last] * rd_q_w[(d + 2) * 64 + lane];
        qd += hidT[(d + 3) * 65 + last] * rd_q_w[(d + 3) * 64 + lane];
    }
    float q = (qa + qb) + (qc + qd);
    float lk = wsum(s * q) * 0.125f;
    if (lane == 0) l4[wid] = lk;
    slN[wid][lane] = s;
    __syncthreads();

    if (wid == 0) {
        float e0 = __expf(l4[0]), e1 = __expf(l4[1]);
        float e2 = __expf(l4[2]), e3 = __expf(l4[3]);
        float dn = e0 + e1 + e2 + e3;
        float r = (e0 * slN[0][lane] + e1 * slN[1][lane]
                 + e2 * slN[2][lane] + e3 * slN[3][lane]) / dn;
        rbuf[lane] = r;
        wb();
        float o0 = out_b[lane], o1 = 0.f, o2 = 0.f, o3 = 0.f;
        #pragma unroll
        for (int hh = 0; hh < 64; hh += 4) {
            o0 += rbuf[hh + 0] * out_w[(hh + 0) * 64 + lane];
            o1 += rbuf[hh + 1] * out_w[(hh + 1) * 64 + lane];
            o2 += rbuf[hh + 2] * out_w[(hh + 2) * 64 + lane];
            o3 += rbuf[hh + 3] * out_w[(hh + 3) * 64 + lane];
        }
        out[(size_t)bid * VOCAB + lane] = ((o0 + o1) + (o2 + o3));
    }
}

extern "C" void kernel_launch(void* const* d_in, const int* in_sizes, int n_in,
                              void* d_out, int out_size, void* d_ws, size_t ws_size,
                              hipStream_t stream) {
    const int*   seq    = (const int*)  d_in[0];
    const float* embed  = (const float*)d_in[1];
    const float* ff1_w  = (const float*)d_in[2];
    const float* ff1_b  = (const float*)d_in[3];
    const float* ff2_w  = (const float*)d_in[4];
    const float* ff2_b  = (const float*)d_in[5];
    const float* enc_g  = (const float*)d_in[6];
    const float* enc_b  = (const float*)d_in[7];
    const float* g1_w   = (const float*)d_in[8];
    const float* g1_b   = (const float*)d_in[9];
    const float* g2_w   = (const float*)d_in[10];
    const float* g2_b   = (const float*)d_in[11];
    const float* rq_w   = (const float*)d_in[12];
    const float* rq_b   = (const float*)d_in[13];
    const float* rk_w   = (const float*)d_in[14];
    const float* rk_b   = (const float*)d_in[15];
    const float* rv_w   = (const float*)d_in[16];
    const float* rv_b   = (const float*)d_in[17];
    const float* rn_g   = (const float*)d_in[18];
    const float* rn_b   = (const float*)d_in[19];
    const float* rd_q_w = (const float*)d_in[20];
    const float* rd_q_b = (const float*)d_in[21];
    const float* out_w  = (const float*)d_in[22];
    const float* out_b  = (const float*)d_in[23];
    float* out = (float*)d_out;

    const int B = in_sizes[0] / LSEQ;

    fused_all<<<B, 256, 0, stream>>>(
        seq, embed, ff1_w, ff1_b, ff2_w, ff2_b, enc_g, enc_b,
        g1_w, g1_b, g2_w, g2_b,
        rq_w, rq_b, rk_w, rk_b, rv_w, rv_b, rn_g, rn_b,
        rd_q_w, rd_q_b, out_w, out_b, out);
}